// Round 1
// baseline (1313.826 us; speedup 1.0000x reference)
//
#include <hip/hip_runtime.h>

#define NODE_CH 128
#define IN_CH   256
#define OUT_CH  256
#define Q_CH    64
#define MAXD    256   // max supported segment degree (avg 32, max ~60 for this input)

// ---------------- index helpers (int32 or int64 input, runtime-detected) ---
__device__ __forceinline__ int load_idx(const void* base, long long i, int is64) {
  if (is64) return (int)((const long long*)base)[i];
  return ((const int*)base)[i];
}

__global__ void detect_kernel(const unsigned int* __restrict__ idx, int* __restrict__ flag) {
  if (threadIdx.x == 0 && blockIdx.x == 0) {
    int allz = 1;
    // if data is int64 (values < 50000), every odd 32-bit word is 0.
    for (int i = 1; i < 32; i += 2) allz &= (idx[i] == 0u);
    *flag = allz;
  }
}

// ---------------- CSR build ------------------------------------------------
__global__ void hist_kernel(const void* __restrict__ idx, const int* __restrict__ flag,
                            int* __restrict__ nrow, int* __restrict__ hrow, long long E) {
  int is64 = *flag;
  long long i = (long long)blockIdx.x * blockDim.x + threadIdx.x;
  long long stride = (long long)gridDim.x * blockDim.x;
  for (; i < E; i += stride) {
    atomicAdd(&nrow[load_idx(idx, i, is64) + 1], 1);
    atomicAdd(&hrow[load_idx(idx, E + i, is64) + 1], 1);
  }
}

__global__ __launch_bounds__(1024) void scan_kernel(int* __restrict__ nrow, int* __restrict__ ncur,
                                                    int* __restrict__ hrow, int* __restrict__ hcur,
                                                    int nn, int nh) {
  int* arr = (blockIdx.x == 0) ? nrow : hrow;
  int* cur = (blockIdx.x == 0) ? ncur : hcur;
  int n   = (blockIdx.x == 0) ? nn : nh;
  int len = n + 1;
  __shared__ int s[1024];
  int carry = 0;
  for (int base = 0; base < len; base += 1024) {
    int i = base + (int)threadIdx.x;
    int v = (i < len) ? arr[i] : 0;
    s[threadIdx.x] = v;
    __syncthreads();
    for (int off = 1; off < 1024; off <<= 1) {
      int t = (threadIdx.x >= (unsigned)off) ? s[threadIdx.x - off] : 0;
      __syncthreads();
      s[threadIdx.x] += t;
      __syncthreads();
    }
    int incl  = s[threadIdx.x];
    int total = s[1023];
    if (i < len) {
      arr[i] = carry + incl;        // exclusive scan of counts == row start
      if (i < n) cur[i] = carry + incl;
    }
    __syncthreads();
    carry += total;
  }
}

__global__ void scatter_kernel(const void* __restrict__ idx, const int* __restrict__ flag,
                               int* __restrict__ ncur, int* __restrict__ hcur,
                               int* __restrict__ pn, int* __restrict__ ph, long long E) {
  int is64 = *flag;
  long long i = (long long)blockIdx.x * blockDim.x + threadIdx.x;
  long long stride = (long long)gridDim.x * blockDim.x;
  for (; i < E; i += stride) {
    int ni = load_idx(idx, i, is64);
    int hj = load_idx(idx, E + i, is64);
    pn[atomicAdd(&ncur[ni], 1)] = (int)i;
    ph[atomicAdd(&hcur[hj], 1)] = (int)i;
  }
}

// ---------------- f32 tiled GEMM: C[M,N] = A[M,K] @ B[K,N] -----------------
#define GBM 128
#define GBN 64
#define GBK 16

__global__ __launch_bounds__(256) void gemm_f32(const float* __restrict__ A,
                                                const float* __restrict__ B,
                                                float* __restrict__ C,
                                                int M, int N, int K) {
  __shared__ float As[GBK][GBM + 4];
  __shared__ float Bs[GBK][GBN];
  int tid = threadIdx.x;
  int tx = tid & 15;   // 16 col groups of 4
  int ty = tid >> 4;   // 16 row groups of 8
  int row0 = blockIdx.y * GBM;
  int col0 = blockIdx.x * GBN;
  float acc[8][4] = {};
  for (int k0 = 0; k0 < K; k0 += GBK) {
    // A tile: 128x16 floats = 512 float4, 2 per thread
    #pragma unroll
    for (int i = 0; i < 2; ++i) {
      int idx = tid + i * 256;       // 0..511
      int r   = idx >> 2;            // 0..127
      int kq  = (idx & 3) << 2;      // 0,4,8,12
      float4 v = make_float4(0.f, 0.f, 0.f, 0.f);
      int gr = row0 + r;
      if (gr < M) v = *(const float4*)&A[(long long)gr * K + k0 + kq];
      As[kq + 0][r] = v.x; As[kq + 1][r] = v.y; As[kq + 2][r] = v.z; As[kq + 3][r] = v.w;
    }
    // B tile: 16x64 floats = 256 float4, 1 per thread
    {
      int kr = tid >> 4;             // 0..15
      int cq = (tid & 15) << 2;      // 0..60
      *(float4*)&Bs[kr][cq] = *(const float4*)&B[(long long)(k0 + kr) * N + col0 + cq];
    }
    __syncthreads();
    #pragma unroll
    for (int kk = 0; kk < GBK; ++kk) {
      float a[8], b[4];
      *(float4*)&a[0] = *(const float4*)&As[kk][ty * 8];
      *(float4*)&a[4] = *(const float4*)&As[kk][ty * 8 + 4];
      *(float4*)&b[0] = *(const float4*)&Bs[kk][tx * 4];
      #pragma unroll
      for (int i = 0; i < 8; ++i)
        #pragma unroll
        for (int j = 0; j < 4; ++j)
          acc[i][j] = fmaf(a[i], b[j], acc[i][j]);
    }
    __syncthreads();
  }
  #pragma unroll
  for (int i = 0; i < 8; ++i) {
    int gr = row0 + ty * 8 + i;
    if (gr < M) *(float4*)&C[(long long)gr * N + col0 + tx * 4] = *(float4*)&acc[i][0];
  }
}

// ---------------- fused per-segment attention (one wave per segment) -------
// scores: leaky_relu(dot64(attn_seg[seg], attn_oth[other])) -> segment softmax
// out[seg] = sum_e (scale * softmax_e) * val[other_e]   (ACC_CH channels)
template <int ACC_CH>
__global__ __launch_bounds__(256) void stage_kernel(
    const int* __restrict__ row, const int* __restrict__ perm,
    const void* __restrict__ idxbase, const int* __restrict__ flagp,
    long long other_off,
    const float* __restrict__ attn_seg,   // [n_seg, 64]
    const float* __restrict__ attn_oth,   // [*, 64]
    const float* __restrict__ val,        // [*, ACC_CH]
    float* __restrict__ out,              // [n_seg, ACC_CH]
    int n_seg) {
  __shared__ float sc_all[4][MAXD];
  int wave = threadIdx.x >> 6;
  int lane = threadIdx.x & 63;
  int seg = blockIdx.x * 4 + wave;
  bool active = (seg < n_seg);
  int segc = active ? seg : 0;
  int is64 = *flagp;
  int beg = row[segc];
  int end = row[segc + 1];
  int cnt = active ? min(end - beg, MAXD) : 0;
  float* sc = sc_all[wave];

  int sub = lane >> 4;        // which of 4 edges in the group
  int qi  = lane & 15;        // channel quad within 64
  float4 a = *(const float4*)&attn_seg[(long long)segc * Q_CH + qi * 4];

  // pass 1: raw scores + running max
  float m = -3.402823466e38f;
  for (int g = 0; g < cnt; g += 4) {
    int ei = g + sub;
    float s = 0.f;
    if (ei < cnt) {
      int e   = perm[beg + ei];
      int oth = load_idx(idxbase, other_off + e, is64);
      float4 b = *(const float4*)&attn_oth[(long long)oth * Q_CH + qi * 4];
      s = a.x * b.x + a.y * b.y + a.z * b.z + a.w * b.w;
    }
    s += __shfl_xor(s, 1); s += __shfl_xor(s, 2);
    s += __shfl_xor(s, 4); s += __shfl_xor(s, 8);
    if (ei < cnt) {
      s = (s > 0.f) ? s : 0.2f * s;
      if (qi == 0) sc[ei] = s;
      m = fmaxf(m, s);
    }
  }
  #pragma unroll
  for (int o = 1; o < 64; o <<= 1) m = fmaxf(m, __shfl_xor(m, o));
  __syncthreads();

  // pass 2: exp + sum
  float sum = 0.f;
  for (int i = lane; i < cnt; i += 64) {
    float ex = expf(sc[i] - m);
    sc[i] = ex;
    sum += ex;
  }
  #pragma unroll
  for (int o = 1; o < 64; o <<= 1) sum += __shfl_xor(sum, o);
  float inv = 0.125f / (sum + 1e-16f);   // scale = 1/sqrt(64)
  __syncthreads();

  // pass 3: weighted accumulate of val rows
  float acc[ACC_CH / 64] = {};
  for (int i = 0; i < cnt; ++i) {
    int e   = perm[beg + i];
    int oth = load_idx(idxbase, other_off + e, is64);
    float c = sc[i] * inv;
    const float* vp = &val[(long long)oth * ACC_CH];
    #pragma unroll
    for (int k = 0; k < ACC_CH / 64; ++k) acc[k] = fmaf(c, vp[lane + k * 64], acc[k]);
  }
  if (active) {
    #pragma unroll
    for (int k = 0; k < ACC_CH / 64; ++k)
      out[(long long)seg * ACC_CH + lane + k * 64] = acc[k];
  }
}

// ---------------- host ------------------------------------------------------
extern "C" void kernel_launch(void* const* d_in, const int* in_sizes, int n_in,
                              void* d_out, int out_size, void* d_ws, size_t ws_size,
                              hipStream_t stream) {
  const float* p  = (const float*)d_in[0];
  const float* q  = (const float*)d_in[1];
  const void*  hidx = d_in[2];
  const float* w1 = (const float*)d_in[3];
  const float* w2 = (const float*)d_in[4];
  const float* w3 = (const float*)d_in[5];
  const float* w4 = (const float*)d_in[6];
  const float* w5 = (const float*)d_in[7];
  const float* w6 = (const float*)d_in[8];

  int nn = in_sizes[0] / NODE_CH;
  int nh = in_sizes[1] / IN_CH;
  long long E = (long long)in_sizes[2] / 2;

  char* ws = (char*)d_ws;
  size_t off = 0;
  auto alloc = [&](size_t b) { size_t r = off; off += (b + 255) & ~(size_t)255; return r; };
  size_t o_flag = alloc(4);
  size_t o_nrow = alloc((size_t)(nn + 1) * 4);
  size_t o_hrow = alloc((size_t)(nh + 1) * 4);
  size_t o_ncur = alloc((size_t)nn * 4);
  size_t o_hcur = alloc((size_t)nh * 4);
  size_t o_pn   = alloc((size_t)E * 4);
  size_t o_ph   = alloc((size_t)E * 4);
  size_t o_qp   = alloc((size_t)nh * NODE_CH * 4);
  size_t o_qpp  = alloc((size_t)nh * Q_CH * 4);
  size_t o_qppp = alloc((size_t)nn * Q_CH * 4);
  size_t o_pout = alloc((size_t)nn * NODE_CH * 4);
  size_t o_pp   = alloc((size_t)nn * OUT_CH * 4);
  // stage-2 aliases (q_pp / q_ppp are dead after stage 1)
  size_t o_ppp2 = o_qpp;    // p_pp  [nn,64]
  size_t o_pppp = o_qppp;   // p_ppp [nh,64]
  if (off > ws_size) return;  // workspace too small; fail loudly via validation

  int* flag = (int*)(ws + o_flag);
  int* nrow = (int*)(ws + o_nrow);
  int* hrow = (int*)(ws + o_hrow);
  int* ncur = (int*)(ws + o_ncur);
  int* hcur = (int*)(ws + o_hcur);
  int* pn   = (int*)(ws + o_pn);
  int* ph   = (int*)(ws + o_ph);
  float* qp   = (float*)(ws + o_qp);
  float* qpp  = (float*)(ws + o_qpp);
  float* qppp = (float*)(ws + o_qppp);
  float* pout = (float*)(ws + o_pout);
  float* pp   = (float*)(ws + o_pp);
  float* ppp2 = (float*)(ws + o_ppp2);
  float* pppp = (float*)(ws + o_pppp);

  hipMemsetAsync(nrow, 0, (size_t)(nn + 1) * 4, stream);
  hipMemsetAsync(hrow, 0, (size_t)(nh + 1) * 4, stream);
  detect_kernel<<<1, 64, 0, stream>>>((const unsigned int*)hidx, flag);
  hist_kernel<<<2048, 256, 0, stream>>>(hidx, flag, nrow, hrow, E);
  scan_kernel<<<2, 1024, 0, stream>>>(nrow, ncur, hrow, hcur, nn, nh);
  scatter_kernel<<<2048, 256, 0, stream>>>(hidx, flag, ncur, hcur, pn, ph, E);

  // stage-1 projections
  gemm_f32<<<dim3(NODE_CH / GBN, (nh + GBM - 1) / GBM), 256, 0, stream>>>(q, w1, qp,   nh, NODE_CH, IN_CH);
  gemm_f32<<<dim3(Q_CH / GBN,    (nh + GBM - 1) / GBM), 256, 0, stream>>>(q, w2, qpp,  nh, Q_CH,    IN_CH);
  gemm_f32<<<dim3(Q_CH / GBN,    (nn + GBM - 1) / GBM), 256, 0, stream>>>(p, w3, qppp, nn, Q_CH,    NODE_CH);

  // stage 1: hedge -> node
  stage_kernel<NODE_CH><<<(nn + 3) / 4, 256, 0, stream>>>(
      nrow, pn, hidx, flag, E, qppp, qpp, qp, pout, nn);

  // stage-2 projections
  gemm_f32<<<dim3(OUT_CH / GBN, (nn + GBM - 1) / GBM), 256, 0, stream>>>(pout, w4, pp,   nn, OUT_CH, NODE_CH);
  gemm_f32<<<dim3(Q_CH / GBN,   (nn + GBM - 1) / GBM), 256, 0, stream>>>(pout, w5, ppp2, nn, Q_CH,   NODE_CH);
  gemm_f32<<<dim3(Q_CH / GBN,   (nh + GBM - 1) / GBM), 256, 0, stream>>>(q,    w6, pppp, nh, Q_CH,   IN_CH);

  // stage 2: node -> hedge (writes final output)
  stage_kernel<OUT_CH><<<(nh + 3) / 4, 256, 0, stream>>>(
      hrow, ph, hidx, flag, 0LL, pppp, ppp2, pp, (float*)d_out, nh);
}

// Round 2
// 983.041 us; speedup vs baseline: 1.3365x; 1.3365x over previous
//
#include <hip/hip_runtime.h>
#include <hip/hip_bf16.h>

#define NODE_CH 128
#define IN_CH   256
#define OUT_CH  256
#define Q_CH    64
#define MAXD    256   // max supported segment degree (Poisson mean 32 -> max ~70)

// ---------------- index helpers (int32 or int64 input, runtime-detected) ---
__device__ __forceinline__ int load_idx(const void* base, long long i, int is64) {
  if (is64) return (int)((const long long*)base)[i];
  return ((const int*)base)[i];
}

__global__ void detect_kernel(const unsigned int* __restrict__ idx, int* __restrict__ flag) {
  if (threadIdx.x == 0 && blockIdx.x == 0) {
    int allz = 1;
    // if data is int64 (values < 50000), every odd 32-bit word is 0.
    for (int i = 1; i < 32; i += 2) allz &= (idx[i] == 0u);
    *flag = allz;
  }
}

// ---------------- CSR build ------------------------------------------------
__global__ void hist_kernel(const void* __restrict__ idx, const int* __restrict__ flag,
                            int* __restrict__ nrow, int* __restrict__ hrow, long long E) {
  int is64 = *flag;
  long long i = (long long)blockIdx.x * blockDim.x + threadIdx.x;
  long long stride = (long long)gridDim.x * blockDim.x;
  for (; i < E; i += stride) {
    atomicAdd(&nrow[load_idx(idx, i, is64) + 1], 1);
    atomicAdd(&hrow[load_idx(idx, E + i, is64) + 1], 1);
  }
}

__global__ __launch_bounds__(1024) void scan_kernel(int* __restrict__ nrow, int* __restrict__ ncur,
                                                    int* __restrict__ hrow, int* __restrict__ hcur,
                                                    int nn, int nh) {
  int* arr = (blockIdx.x == 0) ? nrow : hrow;
  int* cur = (blockIdx.x == 0) ? ncur : hcur;
  int n   = (blockIdx.x == 0) ? nn : nh;
  int len = n + 1;
  __shared__ int s[1024];
  int carry = 0;
  for (int base = 0; base < len; base += 1024) {
    int i = base + (int)threadIdx.x;
    int v = (i < len) ? arr[i] : 0;
    s[threadIdx.x] = v;
    __syncthreads();
    for (int off = 1; off < 1024; off <<= 1) {
      int t = (threadIdx.x >= (unsigned)off) ? s[threadIdx.x - off] : 0;
      __syncthreads();
      s[threadIdx.x] += t;
      __syncthreads();
    }
    int incl  = s[threadIdx.x];
    int total = s[1023];
    if (i < len) {
      arr[i] = carry + incl;        // exclusive scan of counts == row start
      if (i < n) cur[i] = carry + incl;
    }
    __syncthreads();
    carry += total;
  }
}

// stores the OTHER endpoint directly into the CSR slot (no edge-id indirection)
__global__ void scatter_kernel(const void* __restrict__ idx, const int* __restrict__ flag,
                               int* __restrict__ ncur, int* __restrict__ hcur,
                               int* __restrict__ pn, int* __restrict__ ph, long long E) {
  int is64 = *flag;
  long long i = (long long)blockIdx.x * blockDim.x + threadIdx.x;
  long long stride = (long long)gridDim.x * blockDim.x;
  for (; i < E; i += stride) {
    int ni = load_idx(idx, i, is64);
    int hj = load_idx(idx, E + i, is64);
    pn[atomicAdd(&ncur[ni], 1)] = hj;   // node-CSR slot holds hedge id
    ph[atomicAdd(&hcur[hj], 1)] = ni;   // hedge-CSR slot holds node id
  }
}

// ---------------- f32 tiled GEMM: C[M,N] = A[M,K] @ B[K,N] -----------------
// C (f32) and Cb (bf16) are each optional.
#define GBM 128
#define GBN 64
#define GBK 16

__device__ __forceinline__ unsigned short f2bf(float f) {
  __hip_bfloat16 h = __float2bfloat16(f);
  return *reinterpret_cast<unsigned short*>(&h);
}

__global__ __launch_bounds__(256) void gemm_f32(const float* __restrict__ A,
                                                const float* __restrict__ B,
                                                float* __restrict__ C,
                                                unsigned short* __restrict__ Cb,
                                                int M, int N, int K) {
  __shared__ float As[GBK][GBM + 4];
  __shared__ float Bs[GBK][GBN];
  int tid = threadIdx.x;
  int tx = tid & 15;   // 16 col groups of 4
  int ty = tid >> 4;   // 16 row groups of 8
  int row0 = blockIdx.y * GBM;
  int col0 = blockIdx.x * GBN;
  float acc[8][4] = {};
  for (int k0 = 0; k0 < K; k0 += GBK) {
    #pragma unroll
    for (int i = 0; i < 2; ++i) {
      int idx = tid + i * 256;       // 0..511
      int r   = idx >> 2;            // 0..127
      int kq  = (idx & 3) << 2;      // 0,4,8,12
      float4 v = make_float4(0.f, 0.f, 0.f, 0.f);
      int gr = row0 + r;
      if (gr < M) v = *(const float4*)&A[(long long)gr * K + k0 + kq];
      As[kq + 0][r] = v.x; As[kq + 1][r] = v.y; As[kq + 2][r] = v.z; As[kq + 3][r] = v.w;
    }
    {
      int kr = tid >> 4;             // 0..15
      int cq = (tid & 15) << 2;      // 0..60
      *(float4*)&Bs[kr][cq] = *(const float4*)&B[(long long)(k0 + kr) * N + col0 + cq];
    }
    __syncthreads();
    #pragma unroll
    for (int kk = 0; kk < GBK; ++kk) {
      float a[8], b[4];
      *(float4*)&a[0] = *(const float4*)&As[kk][ty * 8];
      *(float4*)&a[4] = *(const float4*)&As[kk][ty * 8 + 4];
      *(float4*)&b[0] = *(const float4*)&Bs[kk][tx * 4];
      #pragma unroll
      for (int i = 0; i < 8; ++i)
        #pragma unroll
        for (int j = 0; j < 4; ++j)
          acc[i][j] = fmaf(a[i], b[j], acc[i][j]);
    }
    __syncthreads();
  }
  #pragma unroll
  for (int i = 0; i < 8; ++i) {
    int gr = row0 + ty * 8 + i;
    if (gr < M) {
      if (C)  *(float4*)&C[(long long)gr * N + col0 + tx * 4] = *(float4*)&acc[i][0];
      if (Cb) {
        ushort4 h;
        h.x = f2bf(acc[i][0]); h.y = f2bf(acc[i][1]);
        h.z = f2bf(acc[i][2]); h.w = f2bf(acc[i][3]);
        *(ushort4*)&Cb[(long long)gr * N + col0 + tx * 4] = h;
      }
    }
  }
}

// ---------------- fused per-segment attention (one wave per segment) -------
// scores: leaky_relu(dot64(attn_seg[seg], attn_oth[oth])) -> segment softmax
// out[seg] = sum_e (scale * softmax_e) * val[oth_e]   (ACC_CH channels, val bf16)
__device__ __forceinline__ float bf_lo(unsigned int u) { return __uint_as_float(u << 16); }
__device__ __forceinline__ float bf_hi(unsigned int u) { return __uint_as_float(u & 0xffff0000u); }

template <int ACC_CH>
__global__ __launch_bounds__(256) void stage_kernel(
    const int* __restrict__ row,       // [n_seg+1] CSR row starts
    const int* __restrict__ oth_arr,   // [E] other-side endpoint per slot
    const float* __restrict__ attn_seg,   // [n_seg, 64] f32
    const float* __restrict__ attn_oth,   // [*, 64] f32
    const unsigned short* __restrict__ valb,  // [*, ACC_CH] bf16
    float* __restrict__ out,              // [n_seg, ACC_CH] f32
    int n_seg) {
  __shared__ float sc_all[4][MAXD];
  __shared__ int   so_all[4][MAXD];
  int wave = threadIdx.x >> 6;
  int lane = threadIdx.x & 63;
  int seg = blockIdx.x * 4 + wave;
  bool active = (seg < n_seg);
  int segc = active ? seg : 0;
  int beg = row[segc];
  int end = row[segc + 1];
  int cnt = active ? min(end - beg, MAXD) : 0;
  float* sc = sc_all[wave];
  int*   so = so_all[wave];

  int sub = lane >> 4;        // which of 4 edges in the group
  int qi  = lane & 15;        // channel quad within 64
  float4 a = *(const float4*)&attn_seg[(long long)segc * Q_CH + qi * 4];

  // pass 1: raw scores + running max; cache oth in LDS
  float m = -3.402823466e38f;
  for (int g = 0; g < cnt; g += 4) {
    int ei = g + sub;
    float s = 0.f;
    int oth = 0;
    if (ei < cnt) {
      oth = oth_arr[beg + ei];
      float4 b = *(const float4*)&attn_oth[(long long)oth * Q_CH + qi * 4];
      s = a.x * b.x + a.y * b.y + a.z * b.z + a.w * b.w;
    }
    s += __shfl_xor(s, 1); s += __shfl_xor(s, 2);
    s += __shfl_xor(s, 4); s += __shfl_xor(s, 8);
    if (ei < cnt) {
      s = (s > 0.f) ? s : 0.2f * s;
      if (qi == 0) { sc[ei] = s; so[ei] = oth; }
      m = fmaxf(m, s);
    }
  }
  #pragma unroll
  for (int o = 1; o < 64; o <<= 1) m = fmaxf(m, __shfl_xor(m, o));
  __syncthreads();

  // pass 2: exp + sum
  float sum = 0.f;
  for (int i = lane; i < cnt; i += 64) {
    float ex = expf(sc[i] - m);
    sc[i] = ex;
    sum += ex;
  }
  #pragma unroll
  for (int o = 1; o < 64; o <<= 1) sum += __shfl_xor(sum, o);
  float inv = 0.125f / (sum + 1e-16f);   // scale = 1/sqrt(64)
  __syncthreads();

  // pass 3: weighted accumulate of bf16 val rows
  constexpr int VPL = ACC_CH / 64;    // 2 or 4 bf16 channels per lane
  float acc[VPL] = {};
  for (int i = 0; i < cnt; ++i) {
    int oth = so[i];
    float c = sc[i] * inv;
    const unsigned short* vp = &valb[(long long)oth * ACC_CH + lane * VPL];
    if constexpr (VPL == 2) {
      unsigned int u = *(const unsigned int*)vp;
      acc[0] = fmaf(c, bf_lo(u), acc[0]);
      acc[1] = fmaf(c, bf_hi(u), acc[1]);
    } else {
      uint2 u = *(const uint2*)vp;
      acc[0] = fmaf(c, bf_lo(u.x), acc[0]);
      acc[1] = fmaf(c, bf_hi(u.x), acc[1]);
      acc[2] = fmaf(c, bf_lo(u.y), acc[2]);
      acc[3] = fmaf(c, bf_hi(u.y), acc[3]);
    }
  }
  if (active) {
    if constexpr (VPL == 2) {
      *(float2*)&out[(long long)seg * ACC_CH + lane * 2] = make_float2(acc[0], acc[1]);
    } else {
      *(float4*)&out[(long long)seg * ACC_CH + lane * 4] = make_float4(acc[0], acc[1], acc[2], acc[3]);
    }
  }
}

// ---------------- host ------------------------------------------------------
extern "C" void kernel_launch(void* const* d_in, const int* in_sizes, int n_in,
                              void* d_out, int out_size, void* d_ws, size_t ws_size,
                              hipStream_t stream) {
  const float* p  = (const float*)d_in[0];
  const float* q  = (const float*)d_in[1];
  const void*  hidx = d_in[2];
  const float* w1 = (const float*)d_in[3];
  const float* w2 = (const float*)d_in[4];
  const float* w3 = (const float*)d_in[5];
  const float* w4 = (const float*)d_in[6];
  const float* w5 = (const float*)d_in[7];
  const float* w6 = (const float*)d_in[8];

  int nn = in_sizes[0] / NODE_CH;
  int nh = in_sizes[1] / IN_CH;
  long long E = (long long)in_sizes[2] / 2;

  char* ws = (char*)d_ws;
  size_t off = 0;
  auto alloc = [&](size_t b) { size_t r = off; off += (b + 255) & ~(size_t)255; return r; };
  size_t o_flag = alloc(4);
  size_t o_nrow = alloc((size_t)(nn + 1) * 4);
  size_t o_hrow = alloc((size_t)(nh + 1) * 4);
  size_t o_ncur = alloc((size_t)nn * 4);
  size_t o_hcur = alloc((size_t)nh * 4);
  size_t o_pn   = alloc((size_t)E * 4);
  size_t o_ph   = alloc((size_t)E * 4);
  size_t o_qpb  = alloc((size_t)nh * NODE_CH * 2);   // q_p  bf16 [H,128]
  size_t o_qpp  = alloc((size_t)nh * Q_CH * 4);      // q_pp f32 [H,64]
  size_t o_qppp = alloc((size_t)nn * Q_CH * 4);      // q_ppp f32 [N,64]
  size_t o_pout = alloc((size_t)nn * NODE_CH * 4);   // p_out f32 [N,128]
  size_t o_ppb  = alloc((size_t)nn * OUT_CH * 2);    // p_p  bf16 [N,256]
  // stage-2 aliases (q_pp / q_ppp dead after stage 1)
  size_t o_ppp2 = o_qpp;    // p_pp  f32 [N,64]
  size_t o_pppp = o_qppp;   // p_ppp f32 [H,64]
  if (off > ws_size) return;

  int* flag = (int*)(ws + o_flag);
  int* nrow = (int*)(ws + o_nrow);
  int* hrow = (int*)(ws + o_hrow);
  int* ncur = (int*)(ws + o_ncur);
  int* hcur = (int*)(ws + o_hcur);
  int* pn   = (int*)(ws + o_pn);
  int* ph   = (int*)(ws + o_ph);
  unsigned short* qpb = (unsigned short*)(ws + o_qpb);
  float* qpp  = (float*)(ws + o_qpp);
  float* qppp = (float*)(ws + o_qppp);
  float* pout = (float*)(ws + o_pout);
  unsigned short* ppb = (unsigned short*)(ws + o_ppb);
  float* ppp2 = (float*)(ws + o_ppp2);
  float* pppp = (float*)(ws + o_pppp);

  hipMemsetAsync(nrow, 0, (size_t)(nn + 1) * 4, stream);
  hipMemsetAsync(hrow, 0, (size_t)(nh + 1) * 4, stream);
  detect_kernel<<<1, 64, 0, stream>>>((const unsigned int*)hidx, flag);
  hist_kernel<<<2048, 256, 0, stream>>>(hidx, flag, nrow, hrow, E);
  scan_kernel<<<2, 1024, 0, stream>>>(nrow, ncur, hrow, hcur, nn, nh);
  scatter_kernel<<<2048, 256, 0, stream>>>(hidx, flag, ncur, hcur, pn, ph, E);

  // stage-1 projections
  gemm_f32<<<dim3(NODE_CH / GBN, (nh + GBM - 1) / GBM), 256, 0, stream>>>(q, w1, nullptr, qpb, nh, NODE_CH, IN_CH);
  gemm_f32<<<dim3(Q_CH / GBN,    (nh + GBM - 1) / GBM), 256, 0, stream>>>(q, w2, qpp,  nullptr, nh, Q_CH, IN_CH);
  gemm_f32<<<dim3(Q_CH / GBN,    (nn + GBM - 1) / GBM), 256, 0, stream>>>(p, w3, qppp, nullptr, nn, Q_CH, NODE_CH);

  // stage 1: hedge -> node  (seg=node, oth=hedge)
  stage_kernel<NODE_CH><<<(nn + 3) / 4, 256, 0, stream>>>(
      nrow, pn, qppp, qpp, qpb, pout, nn);

  // stage-2 projections
  gemm_f32<<<dim3(OUT_CH / GBN, (nn + GBM - 1) / GBM), 256, 0, stream>>>(pout, w4, nullptr, ppb, nn, OUT_CH, NODE_CH);
  gemm_f32<<<dim3(Q_CH / GBN,   (nn + GBM - 1) / GBM), 256, 0, stream>>>(pout, w5, ppp2, nullptr, nn, Q_CH, NODE_CH);
  gemm_f32<<<dim3(Q_CH / GBN,   (nh + GBM - 1) / GBM), 256, 0, stream>>>(q,    w6, pppp, nullptr, nh, Q_CH, IN_CH);

  // stage 2: node -> hedge  (seg=hedge, oth=node) -> final output
  stage_kernel<OUT_CH><<<(nh + 3) / 4, 256, 0, stream>>>(
      hrow, ph, pppp, ppp2, ppb, (float*)d_out, nh);
}

// Round 3
// 552.070 us; speedup vs baseline: 2.3798x; 1.7806x over previous
//
#include <hip/hip_runtime.h>
#include <hip/hip_bf16.h>

#define NODE_CH 128
#define IN_CH   256
#define OUT_CH  256
#define Q_CH    64
#define MAXD    256   // max supported segment degree (Poisson mean 32 -> max ~70)

// bucketed counting-sort parameters
#define W_BITS 7
#define W_SEG  128          // segments per bucket
#define MAX_NB 400          // max buckets per side (50000/128 = 391)
#define CAP    4608         // max edges per bucket (mean 4092, +8 sigma)
#define CHUNK  4096         // edges per bin block

// ---------------- index helpers (int32 or int64 input, runtime-detected) ---
__device__ __forceinline__ int load_idx(const void* base, long long i, int is64) {
  if (is64) return (int)((const long long*)base)[i];
  return ((const int*)base)[i];
}

__global__ void detect_kernel(const unsigned int* __restrict__ idx, int* __restrict__ flag) {
  if (threadIdx.x == 0 && blockIdx.x == 0) {
    int allz = 1;
    // if data is int64 (values < 50000), every odd 32-bit word is 0.
    for (int i = 1; i < 32; i += 2) allz &= (idx[i] == 0u);
    *flag = allz;
  }
}

// ---------------- pass 1: bin edges into segment-range buckets -------------
// payload: (seg & 127) << 16 | other_endpoint   (both ids < 65536)
__global__ __launch_bounds__(512) void bin_kernel(
    const void* __restrict__ idx, const int* __restrict__ flagp,
    int* __restrict__ stagingN, int* __restrict__ stagingH,
    int* __restrict__ gbcntN, int* __restrict__ gbcntH,
    long long E, int NBN, int NBH) {
  __shared__ int ni[CHUNK], hj[CHUNK];
  __shared__ int histN[MAX_NB], histH[MAX_NB];
  __shared__ int baseN[MAX_NB], baseH[MAX_NB];
  __shared__ int curN[MAX_NB],  curH[MAX_NB];
  int is64 = *flagp;
  long long e0 = (long long)blockIdx.x * CHUNK;
  int n = (int)((E - e0 < CHUNK) ? (E - e0) : CHUNK);
  for (int i = threadIdx.x; i < n; i += 512) {
    ni[i] = load_idx(idx, e0 + i, is64);
    hj[i] = load_idx(idx, E + e0 + i, is64);
  }
  for (int i = threadIdx.x; i < MAX_NB; i += 512) {
    histN[i] = 0; histH[i] = 0; curN[i] = 0; curH[i] = 0;
  }
  __syncthreads();
  for (int i = threadIdx.x; i < n; i += 512) {
    atomicAdd(&histN[ni[i] >> W_BITS], 1);
    atomicAdd(&histH[hj[i] >> W_BITS], 1);
  }
  __syncthreads();
  for (int b = threadIdx.x; b < NBN; b += 512)
    if (histN[b]) baseN[b] = atomicAdd(&gbcntN[b], histN[b]);
  for (int b = threadIdx.x; b < NBH; b += 512)
    if (histH[b]) baseH[b] = atomicAdd(&gbcntH[b], histH[b]);
  __syncthreads();
  for (int i = threadIdx.x; i < n; i += 512) {
    int v = ni[i], h = hj[i];
    int bn = v >> W_BITS, bh = h >> W_BITS;
    int rn = baseN[bn] + atomicAdd(&curN[bn], 1);
    if (rn < CAP) stagingN[bn * CAP + rn] = ((v & (W_SEG - 1)) << 16) | h;
    int rh = baseH[bh] + atomicAdd(&curH[bh], 1);
    if (rh < CAP) stagingH[bh * CAP + rh] = ((h & (W_SEG - 1)) << 16) | v;
  }
}

// ---------------- pass 2: per-bucket counting sort -> CSR ------------------
__global__ __launch_bounds__(512) void bucket_sort_kernel(
    const int* __restrict__ stagingN, const int* __restrict__ gbcntN,
    int* __restrict__ rowN, int* __restrict__ csrN, int SN, int NBN,
    const int* __restrict__ stagingH, const int* __restrict__ gbcntH,
    int* __restrict__ rowH, int* __restrict__ csrH, int SH, int NBH,
    long long E) {
  int side = blockIdx.y;
  const int* staging = side ? stagingH : stagingN;
  const int* gbcnt   = side ? gbcntH   : gbcntN;
  int* row = side ? rowH : rowN;
  int* csr = side ? csrH : csrN;
  int S  = side ? SH  : SN;
  int NB = side ? NBH : NBN;
  int b = blockIdx.x;
  if (b >= NB) return;

  __shared__ int eLDS[CAP];
  __shared__ int outb[CAP];
  __shared__ int hist[W_SEG], lstart[W_SEG + 1], cnt[W_SEG];
  __shared__ int red[8];
  __shared__ int basesh;

  int n_b = gbcnt[b];
  int nc = (n_b < CAP) ? n_b : CAP;

  // base = exclusive sum of gbcnt[0..b)
  int partial = 0;
  for (int i = threadIdx.x; i < b; i += 512) partial += gbcnt[i];
  #pragma unroll
  for (int o = 1; o < 64; o <<= 1) partial += __shfl_xor(partial, o);
  if ((threadIdx.x & 63) == 0) red[threadIdx.x >> 6] = partial;
  for (int i = threadIdx.x; i < W_SEG; i += 512) { hist[i] = 0; cnt[i] = 0; }
  __syncthreads();
  if (threadIdx.x == 0) {
    int s = 0;
    #pragma unroll
    for (int w = 0; w < 8; ++w) s += red[w];
    basesh = s;
  }
  __syncthreads();
  int base = basesh;

  for (int i = threadIdx.x; i < nc; i += 512) {
    int e = staging[b * CAP + i];
    eLDS[i] = e;
    atomicAdd(&hist[e >> 16], 1);
  }
  __syncthreads();
  if (threadIdx.x == 0) {
    int acc = 0;
    for (int s = 0; s < W_SEG; ++s) { lstart[s] = acc; acc += hist[s]; }
    lstart[W_SEG] = acc;
  }
  __syncthreads();
  int s0 = b * W_SEG;
  for (int s = threadIdx.x; s < W_SEG; s += 512)
    if (s0 + s < S) row[s0 + s] = base + lstart[s];
  if (b == NB - 1 && threadIdx.x == 0) row[S] = (int)E;
  __syncthreads();
  for (int i = threadIdx.x; i < nc; i += 512) {
    int e = eLDS[i];
    int s = e >> 16;
    int r = atomicAdd(&cnt[s], 1);
    outb[lstart[s] + r] = e & 0xffff;
  }
  __syncthreads();
  for (int i = threadIdx.x; i < nc; i += 512) csr[base + i] = outb[i];
}

// ---------------- f32 tiled GEMM: C[M,N] = A[M,K] @ B[K,N] -----------------
#define GBM 128
#define GBN 64
#define GBK 16

__device__ __forceinline__ unsigned short f2bf(float f) {
  __hip_bfloat16 h = __float2bfloat16(f);
  return *reinterpret_cast<unsigned short*>(&h);
}

__global__ __launch_bounds__(256) void gemm_f32(const float* __restrict__ A,
                                                const float* __restrict__ B,
                                                float* __restrict__ C,
                                                unsigned short* __restrict__ Cb,
                                                int M, int N, int K) {
  __shared__ float As[GBK][GBM + 4];
  __shared__ float Bs[GBK][GBN];
  int tid = threadIdx.x;
  int tx = tid & 15;
  int ty = tid >> 4;
  int row0 = blockIdx.y * GBM;
  int col0 = blockIdx.x * GBN;
  float acc[8][4] = {};
  for (int k0 = 0; k0 < K; k0 += GBK) {
    #pragma unroll
    for (int i = 0; i < 2; ++i) {
      int idx = tid + i * 256;
      int r   = idx >> 2;
      int kq  = (idx & 3) << 2;
      float4 v = make_float4(0.f, 0.f, 0.f, 0.f);
      int gr = row0 + r;
      if (gr < M) v = *(const float4*)&A[(long long)gr * K + k0 + kq];
      As[kq + 0][r] = v.x; As[kq + 1][r] = v.y; As[kq + 2][r] = v.z; As[kq + 3][r] = v.w;
    }
    {
      int kr = tid >> 4;
      int cq = (tid & 15) << 2;
      *(float4*)&Bs[kr][cq] = *(const float4*)&B[(long long)(k0 + kr) * N + col0 + cq];
    }
    __syncthreads();
    #pragma unroll
    for (int kk = 0; kk < GBK; ++kk) {
      float a[8], bb[4];
      *(float4*)&a[0] = *(const float4*)&As[kk][ty * 8];
      *(float4*)&a[4] = *(const float4*)&As[kk][ty * 8 + 4];
      *(float4*)&bb[0] = *(const float4*)&Bs[kk][tx * 4];
      #pragma unroll
      for (int i = 0; i < 8; ++i)
        #pragma unroll
        for (int j = 0; j < 4; ++j)
          acc[i][j] = fmaf(a[i], bb[j], acc[i][j]);
    }
    __syncthreads();
  }
  #pragma unroll
  for (int i = 0; i < 8; ++i) {
    int gr = row0 + ty * 8 + i;
    if (gr < M) {
      if (C)  *(float4*)&C[(long long)gr * N + col0 + tx * 4] = *(float4*)&acc[i][0];
      if (Cb) {
        ushort4 h;
        h.x = f2bf(acc[i][0]); h.y = f2bf(acc[i][1]);
        h.z = f2bf(acc[i][2]); h.w = f2bf(acc[i][3]);
        *(ushort4*)&Cb[(long long)gr * N + col0 + tx * 4] = h;
      }
    }
  }
}

// ---------------- fused per-segment attention (one wave per segment) -------
__device__ __forceinline__ float bf_lo(unsigned int u) { return __uint_as_float(u << 16); }
__device__ __forceinline__ float bf_hi(unsigned int u) { return __uint_as_float(u & 0xffff0000u); }

template <int ACC_CH>
__global__ __launch_bounds__(256) void stage_kernel(
    const int* __restrict__ row,        // [n_seg+1] CSR row starts
    const int* __restrict__ oth_arr,    // [E] other-side endpoint per slot
    const float* __restrict__ attn_seg, // [n_seg, 64] f32
    const float* __restrict__ attn_oth, // [*, 64] f32
    const unsigned short* __restrict__ valb, // [*, ACC_CH] bf16
    float* __restrict__ out,            // [n_seg, ACC_CH] f32
    int n_seg) {
  __shared__ float sc_all[4][MAXD];
  __shared__ int   so_all[4][MAXD];
  int wave = threadIdx.x >> 6;
  int lane = threadIdx.x & 63;
  int seg = blockIdx.x * 4 + wave;
  bool active = (seg < n_seg);
  int segc = active ? seg : 0;
  int beg = row[segc];
  int end = row[segc + 1];
  int cnt = active ? min(end - beg, MAXD) : 0;
  float* sc = sc_all[wave];
  int*   so = so_all[wave];

  int sub = lane >> 4;
  int qi  = lane & 15;
  float4 a = *(const float4*)&attn_seg[(long long)segc * Q_CH + qi * 4];

  float m = -3.402823466e38f;
  for (int g = 0; g < cnt; g += 4) {
    int ei = g + sub;
    float s = 0.f;
    int oth = 0;
    if (ei < cnt) {
      oth = oth_arr[beg + ei];
      float4 b = *(const float4*)&attn_oth[(long long)oth * Q_CH + qi * 4];
      s = a.x * b.x + a.y * b.y + a.z * b.z + a.w * b.w;
    }
    s += __shfl_xor(s, 1); s += __shfl_xor(s, 2);
    s += __shfl_xor(s, 4); s += __shfl_xor(s, 8);
    if (ei < cnt) {
      s = (s > 0.f) ? s : 0.2f * s;
      if (qi == 0) { sc[ei] = s; so[ei] = oth; }
      m = fmaxf(m, s);
    }
  }
  #pragma unroll
  for (int o = 1; o < 64; o <<= 1) m = fmaxf(m, __shfl_xor(m, o));
  __syncthreads();

  float sum = 0.f;
  for (int i = lane; i < cnt; i += 64) {
    float ex = expf(sc[i] - m);
    sc[i] = ex;
    sum += ex;
  }
  #pragma unroll
  for (int o = 1; o < 64; o <<= 1) sum += __shfl_xor(sum, o);
  float inv = 0.125f / (sum + 1e-16f);   // scale = 1/sqrt(64)
  __syncthreads();

  constexpr int VPL = ACC_CH / 64;
  float acc[VPL] = {};
  for (int i = 0; i < cnt; ++i) {
    int oth = so[i];
    float c = sc[i] * inv;
    const unsigned short* vp = &valb[(long long)oth * ACC_CH + lane * VPL];
    if constexpr (VPL == 2) {
      unsigned int u = *(const unsigned int*)vp;
      acc[0] = fmaf(c, bf_lo(u), acc[0]);
      acc[1] = fmaf(c, bf_hi(u), acc[1]);
    } else {
      uint2 u = *(const uint2*)vp;
      acc[0] = fmaf(c, bf_lo(u.x), acc[0]);
      acc[1] = fmaf(c, bf_hi(u.x), acc[1]);
      acc[2] = fmaf(c, bf_lo(u.y), acc[2]);
      acc[3] = fmaf(c, bf_hi(u.y), acc[3]);
    }
  }
  if (active) {
    if constexpr (VPL == 2) {
      *(float2*)&out[(long long)seg * ACC_CH + lane * 2] = make_float2(acc[0], acc[1]);
    } else {
      *(float4*)&out[(long long)seg * ACC_CH + lane * 4] = make_float4(acc[0], acc[1], acc[2], acc[3]);
    }
  }
}

// ---------------- host ------------------------------------------------------
extern "C" void kernel_launch(void* const* d_in, const int* in_sizes, int n_in,
                              void* d_out, int out_size, void* d_ws, size_t ws_size,
                              hipStream_t stream) {
  const float* p  = (const float*)d_in[0];
  const float* q  = (const float*)d_in[1];
  const void*  hidx = d_in[2];
  const float* w1 = (const float*)d_in[3];
  const float* w2 = (const float*)d_in[4];
  const float* w3 = (const float*)d_in[5];
  const float* w4 = (const float*)d_in[6];
  const float* w5 = (const float*)d_in[7];
  const float* w6 = (const float*)d_in[8];

  int nn = in_sizes[0] / NODE_CH;
  int nh = in_sizes[1] / IN_CH;
  long long E = (long long)in_sizes[2] / 2;
  int NBN = (nn + W_SEG - 1) / W_SEG;
  int NBH = (nh + W_SEG - 1) / W_SEG;
  if (NBN > MAX_NB || NBH > MAX_NB || nn > 65536 || nh > 65536) return;

  char* ws = (char*)d_ws;
  size_t off = 0;
  auto alloc = [&](size_t b) { size_t r = off; off += (b + 255) & ~(size_t)255; return r; };
  size_t o_flag  = alloc(4);
  size_t o_rowN  = alloc((size_t)(nn + 1) * 4);
  size_t o_rowH  = alloc((size_t)(nh + 1) * 4);
  size_t o_gbcnt = alloc((size_t)(NBN + NBH) * 4);
  size_t o_pn    = alloc((size_t)E * 4);
  size_t o_ph    = alloc((size_t)E * 4);
  size_t o_qpb   = alloc((size_t)nh * NODE_CH * 2);   // q_p  bf16 [H,128]  (aliases stagingN)
  size_t o_qpp   = alloc((size_t)nh * Q_CH * 4);      // q_pp f32 [H,64]    (aliases stagingH)
  size_t o_qppp  = alloc((size_t)nn * Q_CH * 4);      // q_ppp f32 [N,64]
  size_t o_pout  = alloc((size_t)nn * NODE_CH * 4);   // p_out f32 [N,128]
  size_t o_ppb   = alloc((size_t)nn * OUT_CH * 2);    // p_p  bf16 [N,256]
  size_t o_ppp2  = o_qpp;    // p_pp  f32 [N,64]  (q_pp dead after stage 1)
  size_t o_pppp  = o_qppp;   // p_ppp f32 [H,64]  (q_ppp dead after stage 1)
  // staging aliases (dead before gemms write qpb/qpp)
  size_t need_stg = (size_t)MAX_NB * CAP * 4;   // 7.37 MB per side
  size_t o_stgN = o_qpb;   // qpb region = nh*128*2 = 12.8 MB >= need
  size_t o_stgH = o_qpp;   // qpp region = nh*64*4  = 12.8 MB >= need
  if ((size_t)nh * NODE_CH * 2 < need_stg) return;
  if ((size_t)nh * Q_CH * 4 < need_stg) return;
  if (off > ws_size) return;

  int* flag   = (int*)(ws + o_flag);
  int* rowN   = (int*)(ws + o_rowN);
  int* rowH   = (int*)(ws + o_rowH);
  int* gbcntN = (int*)(ws + o_gbcnt);
  int* gbcntH = gbcntN + NBN;
  int* pn     = (int*)(ws + o_pn);
  int* ph     = (int*)(ws + o_ph);
  int* stgN   = (int*)(ws + o_stgN);
  int* stgH   = (int*)(ws + o_stgH);
  unsigned short* qpb = (unsigned short*)(ws + o_qpb);
  float* qpp  = (float*)(ws + o_qpp);
  float* qppp = (float*)(ws + o_qppp);
  float* pout = (float*)(ws + o_pout);
  unsigned short* ppb = (unsigned short*)(ws + o_ppb);
  float* ppp2 = (float*)(ws + o_ppp2);
  float* pppp = (float*)(ws + o_pppp);

  hipMemsetAsync(gbcntN, 0, (size_t)(NBN + NBH) * 4, stream);
  detect_kernel<<<1, 64, 0, stream>>>((const unsigned int*)hidx, flag);

  int nblk = (int)((E + CHUNK - 1) / CHUNK);
  bin_kernel<<<nblk, 512, 0, stream>>>(hidx, flag, stgN, stgH, gbcntN, gbcntH, E, NBN, NBH);
  int nbmax = NBN > NBH ? NBN : NBH;
  bucket_sort_kernel<<<dim3(nbmax, 2), 512, 0, stream>>>(
      stgN, gbcntN, rowN, pn, nn, NBN,
      stgH, gbcntH, rowH, ph, nh, NBH, E);

  // stage-1 projections
  gemm_f32<<<dim3(NODE_CH / GBN, (nh + GBM - 1) / GBM), 256, 0, stream>>>(q, w1, nullptr, qpb, nh, NODE_CH, IN_CH);
  gemm_f32<<<dim3(Q_CH / GBN,    (nh + GBM - 1) / GBM), 256, 0, stream>>>(q, w2, qpp,  nullptr, nh, Q_CH, IN_CH);
  gemm_f32<<<dim3(Q_CH / GBN,    (nn + GBM - 1) / GBM), 256, 0, stream>>>(p, w3, qppp, nullptr, nn, Q_CH, NODE_CH);

  // stage 1: hedge -> node  (seg=node, oth=hedge)
  stage_kernel<NODE_CH><<<(nn + 3) / 4, 256, 0, stream>>>(
      rowN, pn, qppp, qpp, qpb, pout, nn);

  // stage-2 projections
  gemm_f32<<<dim3(OUT_CH / GBN, (nn + GBM - 1) / GBM), 256, 0, stream>>>(pout, w4, nullptr, ppb, nn, OUT_CH, NODE_CH);
  gemm_f32<<<dim3(Q_CH / GBN,   (nn + GBM - 1) / GBM), 256, 0, stream>>>(pout, w5, ppp2, nullptr, nn, Q_CH, NODE_CH);
  gemm_f32<<<dim3(Q_CH / GBN,   (nh + GBM - 1) / GBM), 256, 0, stream>>>(q,    w6, pppp, nullptr, nh, Q_CH, IN_CH);

  // stage 2: node -> hedge  (seg=hedge, oth=node) -> final output
  stage_kernel<OUT_CH><<<(nh + 3) / 4, 256, 0, stream>>>(
      rowH, ph, pppp, ppp2, ppb, (float*)d_out, nh);
}

// Round 4
// 511.553 us; speedup vs baseline: 2.5683x; 1.0792x over previous
//
#include <hip/hip_runtime.h>
#include <hip/hip_bf16.h>
#include <hip/hip_fp16.h>

#define NODE_CH 128
#define IN_CH   256
#define OUT_CH  256
#define Q_CH    64

// bucketed counting-sort parameters
#define W_BITS 7
#define W_SEG  128          // segments per bucket
#define MAX_NB 400          // max buckets per side (50000/128 = 391)
#define CAP    4608         // max edges per bucket (mean 4092, +8 sigma)
#define CHUNK  4096         // edges per bin block

// ---------------- fp16 helpers ---------------------------------------------
__device__ __forceinline__ float2 h2_to_f2(unsigned int u) {
  __half2 h; *reinterpret_cast<unsigned int*>(&h) = u;
  return __half22float2(h);
}
__device__ __forceinline__ unsigned int f2_to_h2(float x, float y) {
  __half2 h = __floats2half2_rn(x, y);
  return *reinterpret_cast<unsigned int*>(&h);
}
__device__ __forceinline__ unsigned short f2h(float f) {
  __half h = __float2half_rn(f);
  return *reinterpret_cast<unsigned short*>(&h);
}

// ---------------- index helpers (int32 or int64 input, runtime-detected) ---
__device__ __forceinline__ int load_idx(const void* base, long long i, int is64) {
  if (is64) return (int)((const long long*)base)[i];
  return ((const int*)base)[i];
}

__global__ void detect_kernel(const unsigned int* __restrict__ idx, int* __restrict__ flag) {
  if (threadIdx.x == 0 && blockIdx.x == 0) {
    int allz = 1;
    for (int i = 1; i < 32; i += 2) allz &= (idx[i] == 0u);
    *flag = allz;
  }
}

// ---------------- pass 1: bin edges into segment-range buckets -------------
__global__ __launch_bounds__(512) void bin_kernel(
    const void* __restrict__ idx, const int* __restrict__ flagp,
    int* __restrict__ stagingN, int* __restrict__ stagingH,
    int* __restrict__ gbcntN, int* __restrict__ gbcntH,
    long long E, int NBN, int NBH) {
  __shared__ int ni[CHUNK], hj[CHUNK];
  __shared__ int histN[MAX_NB], histH[MAX_NB];
  __shared__ int baseN[MAX_NB], baseH[MAX_NB];
  __shared__ int curN[MAX_NB],  curH[MAX_NB];
  int is64 = *flagp;
  long long e0 = (long long)blockIdx.x * CHUNK;
  int n = (int)((E - e0 < CHUNK) ? (E - e0) : CHUNK);
  for (int i = threadIdx.x; i < n; i += 512) {
    ni[i] = load_idx(idx, e0 + i, is64);
    hj[i] = load_idx(idx, E + e0 + i, is64);
  }
  for (int i = threadIdx.x; i < MAX_NB; i += 512) {
    histN[i] = 0; histH[i] = 0; curN[i] = 0; curH[i] = 0;
  }
  __syncthreads();
  for (int i = threadIdx.x; i < n; i += 512) {
    atomicAdd(&histN[ni[i] >> W_BITS], 1);
    atomicAdd(&histH[hj[i] >> W_BITS], 1);
  }
  __syncthreads();
  for (int b = threadIdx.x; b < NBN; b += 512)
    if (histN[b]) baseN[b] = atomicAdd(&gbcntN[b], histN[b]);
  for (int b = threadIdx.x; b < NBH; b += 512)
    if (histH[b]) baseH[b] = atomicAdd(&gbcntH[b], histH[b]);
  __syncthreads();
  for (int i = threadIdx.x; i < n; i += 512) {
    int v = ni[i], h = hj[i];
    int bn = v >> W_BITS, bh = h >> W_BITS;
    int rn = baseN[bn] + atomicAdd(&curN[bn], 1);
    if (rn < CAP) stagingN[bn * CAP + rn] = ((v & (W_SEG - 1)) << 16) | h;
    int rh = baseH[bh] + atomicAdd(&curH[bh], 1);
    if (rh < CAP) stagingH[bh * CAP + rh] = ((h & (W_SEG - 1)) << 16) | v;
  }
}

// ---------------- pass 2: per-bucket counting sort -> CSR ------------------
__global__ __launch_bounds__(512) void bucket_sort_kernel(
    const int* __restrict__ stagingN, const int* __restrict__ gbcntN,
    int* __restrict__ rowN, int* __restrict__ csrN, int SN, int NBN,
    const int* __restrict__ stagingH, const int* __restrict__ gbcntH,
    int* __restrict__ rowH, int* __restrict__ csrH, int SH, int NBH,
    long long E) {
  int side = blockIdx.y;
  const int* staging = side ? stagingH : stagingN;
  const int* gbcnt   = side ? gbcntH   : gbcntN;
  int* row = side ? rowH : rowN;
  int* csr = side ? csrH : csrN;
  int S  = side ? SH  : SN;
  int NB = side ? NBH : NBN;
  int b = blockIdx.x;
  if (b >= NB) return;

  __shared__ int eLDS[CAP];
  __shared__ int outb[CAP];
  __shared__ int hist[W_SEG], lstart[W_SEG + 1], cnt[W_SEG];
  __shared__ int red[8];
  __shared__ int basesh;

  int n_b = gbcnt[b];
  int nc = (n_b < CAP) ? n_b : CAP;

  int partial = 0;
  for (int i = threadIdx.x; i < b; i += 512) partial += gbcnt[i];
  #pragma unroll
  for (int o = 1; o < 64; o <<= 1) partial += __shfl_xor(partial, o);
  if ((threadIdx.x & 63) == 0) red[threadIdx.x >> 6] = partial;
  for (int i = threadIdx.x; i < W_SEG; i += 512) { hist[i] = 0; cnt[i] = 0; }
  __syncthreads();
  if (threadIdx.x == 0) {
    int s = 0;
    #pragma unroll
    for (int w = 0; w < 8; ++w) s += red[w];
    basesh = s;
  }
  __syncthreads();
  int base = basesh;

  for (int i = threadIdx.x; i < nc; i += 512) {
    int e = staging[b * CAP + i];
    eLDS[i] = e;
    atomicAdd(&hist[e >> 16], 1);
  }
  __syncthreads();
  if (threadIdx.x == 0) {
    int acc = 0;
    for (int s = 0; s < W_SEG; ++s) { lstart[s] = acc; acc += hist[s]; }
    lstart[W_SEG] = acc;
  }
  __syncthreads();
  int s0 = b * W_SEG;
  for (int s = threadIdx.x; s < W_SEG; s += 512)
    if (s0 + s < S) row[s0 + s] = base + lstart[s];
  if (b == NB - 1 && threadIdx.x == 0) row[S] = (int)E;
  __syncthreads();
  for (int i = threadIdx.x; i < nc; i += 512) {
    int e = eLDS[i];
    int s = e >> 16;
    int r = atomicAdd(&cnt[s], 1);
    outb[lstart[s] + r] = e & 0xffff;
  }
  __syncthreads();
  for (int i = threadIdx.x; i < nc; i += 512) csr[base + i] = outb[i];
}

// ---------------- f32 tiled GEMM: C[M,N] = A[M,K] @ B[K,N] -----------------
// optional f32 output (C, ldc) and/or f16 output (C16, ldc16, coloff16)
#define GBM 128
#define GBN 64
#define GBK 16

__global__ __launch_bounds__(256) void gemm_f32(const float* __restrict__ A,
                                                const float* __restrict__ B,
                                                float* __restrict__ C, int ldc,
                                                unsigned short* __restrict__ C16,
                                                int ldc16, int coloff16,
                                                int M, int N, int K) {
  __shared__ float As[GBK][GBM + 4];
  __shared__ float Bs[GBK][GBN];
  int tid = threadIdx.x;
  int tx = tid & 15;
  int ty = tid >> 4;
  int row0 = blockIdx.y * GBM;
  int col0 = blockIdx.x * GBN;
  float acc[8][4] = {};
  for (int k0 = 0; k0 < K; k0 += GBK) {
    #pragma unroll
    for (int i = 0; i < 2; ++i) {
      int idx = tid + i * 256;
      int r   = idx >> 2;
      int kq  = (idx & 3) << 2;
      float4 v = make_float4(0.f, 0.f, 0.f, 0.f);
      int gr = row0 + r;
      if (gr < M) v = *(const float4*)&A[(long long)gr * K + k0 + kq];
      As[kq + 0][r] = v.x; As[kq + 1][r] = v.y; As[kq + 2][r] = v.z; As[kq + 3][r] = v.w;
    }
    {
      int kr = tid >> 4;
      int cq = (tid & 15) << 2;
      *(float4*)&Bs[kr][cq] = *(const float4*)&B[(long long)(k0 + kr) * N + col0 + cq];
    }
    __syncthreads();
    #pragma unroll
    for (int kk = 0; kk < GBK; ++kk) {
      float a[8], bb[4];
      *(float4*)&a[0] = *(const float4*)&As[kk][ty * 8];
      *(float4*)&a[4] = *(const float4*)&As[kk][ty * 8 + 4];
      *(float4*)&bb[0] = *(const float4*)&Bs[kk][tx * 4];
      #pragma unroll
      for (int i = 0; i < 8; ++i)
        #pragma unroll
        for (int j = 0; j < 4; ++j)
          acc[i][j] = fmaf(a[i], bb[j], acc[i][j]);
    }
    __syncthreads();
  }
  #pragma unroll
  for (int i = 0; i < 8; ++i) {
    int gr = row0 + ty * 8 + i;
    if (gr < M) {
      if (C) *(float4*)&C[(long long)gr * ldc + col0 + tx * 4] = *(float4*)&acc[i][0];
      if (C16) {
        ushort4 h;
        h.x = f2h(acc[i][0]); h.y = f2h(acc[i][1]);
        h.z = f2h(acc[i][2]); h.w = f2h(acc[i][3]);
        *(ushort4*)&C16[(long long)gr * ldc16 + coloff16 + col0 + tx * 4] = h;
      }
    }
  }
}

// ---------------- w5 (128,64) -> w5t (64,128) transpose --------------------
__global__ void transpose_w5(const float* __restrict__ w5, float* __restrict__ w5t) {
  int t = blockIdx.x * 256 + threadIdx.x;
  if (t < 128 * 64) { int r = t >> 6, c = t & 63; w5t[c * 128 + r] = w5[r * 64 + c]; }
}

// ---------------- stage 1: packed-row gather, online softmax ---------------
// row layout [n_oth, 128 u32]: words 0..63 = q_pp f32(64), words 64..127 = q_p f16(128)
// out16[seg] = f16( 0.125/sum * sum_e exp(s_e - m) * q_p[oth_e] )
__global__ __launch_bounds__(256) void stage1_fused(
    const int* __restrict__ row, const int* __restrict__ oth_arr,
    const float* __restrict__ segv,          // [n_seg,64] f32 (q_ppp)
    const unsigned int* __restrict__ rows,   // packed
    unsigned short* __restrict__ out16,      // [n_seg,128] f16
    int n_seg) {
  int wave = threadIdx.x >> 6, lane = threadIdx.x & 63;
  int seg = blockIdx.x * 4 + wave;
  if (seg >= n_seg) return;
  int li = lane & 31;
  int grp = lane >> 5;
  int beg = row[seg];
  int cnt = row[seg + 1] - beg;
  float2 a = *(const float2*)&segv[(long long)seg * 64 + li * 2];
  float m = -1e30f, ssum = 0.f;
  float ax = 0.f, ay = 0.f, az = 0.f, aw = 0.f;
  for (int ei = grp; ei < cnt; ei += 2) {
    int o = oth_arr[beg + ei];
    const unsigned int* rp = rows + (long long)o * 128;
    float2 sv = *(const float2*)(rp + li * 2);
    uint2  uv = *(const uint2*)(rp + 64 + li * 2);
    float part = a.x * sv.x + a.y * sv.y;
    #pragma unroll
    for (int d = 1; d < 32; d <<= 1) part += __shfl_xor(part, d);
    float s = part > 0.f ? part : 0.2f * part;
    float mn = fmaxf(m, s);
    float corr = __expf(m - mn);
    float w = __expf(s - mn);
    m = mn;
    ssum = ssum * corr + w;
    float2 v0 = h2_to_f2(uv.x), v1 = h2_to_f2(uv.y);
    ax = ax * corr + w * v0.x;  ay = ay * corr + w * v0.y;
    az = az * corr + w * v1.x;  aw = aw * corr + w * v1.y;
  }
  float m2 = __shfl_xor(m, 32);
  float mm = fmaxf(m, m2);
  float c1 = __expf(m - mm);
  float c2 = __expf(m2 - mm);
  float ssum2 = __shfl_xor(ssum, 32);
  float tot = ssum * c1 + ssum2 * c2;
  float bx = __shfl_xor(ax, 32), by = __shfl_xor(ay, 32);
  float bz = __shfl_xor(az, 32), bw = __shfl_xor(aw, 32);
  ax = ax * c1 + bx * c2;  ay = ay * c1 + by * c2;
  az = az * c1 + bz * c2;  aw = aw * c1 + bw * c2;
  float inv = 0.125f / (tot + 1e-16f);
  if (lane < 32) {
    uint2 o2;
    o2.x = f2_to_h2(ax * inv, ay * inv);
    o2.y = f2_to_h2(az * inv, aw * inv);
    *(uint2*)(out16 + (long long)seg * 128 + li * 4) = o2;
  }
}

// ---------------- stage 2: single f16 row serves score AND value -----------
// score = dot128(G2[seg], pout16[oth]); out[seg] = 0.125/sum * sum_e w_e * pout16[oth_e]
__global__ __launch_bounds__(256) void stage2_fused(
    const int* __restrict__ row, const int* __restrict__ oth_arr,
    const float* __restrict__ segv,           // [n_seg,128] f32 (G2)
    const unsigned int* __restrict__ rows16,  // [n_oth, 64 u32] = 128 f16
    float* __restrict__ out,                  // [n_seg,128] f32
    int n_seg) {
  int wave = threadIdx.x >> 6, lane = threadIdx.x & 63;
  int seg = blockIdx.x * 4 + wave;
  if (seg >= n_seg) return;
  int li = lane & 31;
  int grp = lane >> 5;
  int beg = row[seg];
  int cnt = row[seg + 1] - beg;
  float4 a = *(const float4*)&segv[(long long)seg * 128 + li * 4];
  float m = -1e30f, ssum = 0.f;
  float ax = 0.f, ay = 0.f, az = 0.f, aw = 0.f;
  for (int ei = grp; ei < cnt; ei += 2) {
    int o = oth_arr[beg + ei];
    uint2 uv = ((const uint2*)(rows16 + (long long)o * 64))[li];
    float2 v0 = h2_to_f2(uv.x), v1 = h2_to_f2(uv.y);
    float part = a.x * v0.x + a.y * v0.y + a.z * v1.x + a.w * v1.y;
    #pragma unroll
    for (int d = 1; d < 32; d <<= 1) part += __shfl_xor(part, d);
    float s = part > 0.f ? part : 0.2f * part;
    float mn = fmaxf(m, s);
    float corr = __expf(m - mn);
    float w = __expf(s - mn);
    m = mn;
    ssum = ssum * corr + w;
    ax = ax * corr + w * v0.x;  ay = ay * corr + w * v0.y;
    az = az * corr + w * v1.x;  aw = aw * corr + w * v1.y;
  }
  float m2 = __shfl_xor(m, 32);
  float mm = fmaxf(m, m2);
  float c1 = __expf(m - mm);
  float c2 = __expf(m2 - mm);
  float ssum2 = __shfl_xor(ssum, 32);
  float tot = ssum * c1 + ssum2 * c2;
  float bx = __shfl_xor(ax, 32), by = __shfl_xor(ay, 32);
  float bz = __shfl_xor(az, 32), bw = __shfl_xor(aw, 32);
  ax = ax * c1 + bx * c2;  ay = ay * c1 + by * c2;
  az = az * c1 + bz * c2;  aw = aw * c1 + bw * c2;
  float inv = 0.125f / (tot + 1e-16f);
  if (lane < 32) {
    float4 o4 = make_float4(ax * inv, ay * inv, az * inv, aw * inv);
    *(float4*)(out + (long long)seg * 128 + li * 4) = o4;
  }
}

// ---------------- host ------------------------------------------------------
extern "C" void kernel_launch(void* const* d_in, const int* in_sizes, int n_in,
                              void* d_out, int out_size, void* d_ws, size_t ws_size,
                              hipStream_t stream) {
  const float* p  = (const float*)d_in[0];
  const float* q  = (const float*)d_in[1];
  const void*  hidx = d_in[2];
  const float* w1 = (const float*)d_in[3];
  const float* w2 = (const float*)d_in[4];
  const float* w3 = (const float*)d_in[5];
  const float* w4 = (const float*)d_in[6];
  const float* w5 = (const float*)d_in[7];
  const float* w6 = (const float*)d_in[8];

  int nn = in_sizes[0] / NODE_CH;
  int nh = in_sizes[1] / IN_CH;
  long long E = (long long)in_sizes[2] / 2;
  int NBN = (nn + W_SEG - 1) / W_SEG;
  int NBH = (nh + W_SEG - 1) / W_SEG;
  if (NBN > MAX_NB || NBH > MAX_NB || nn > 65536 || nh > 65536) return;
  int mx = nn > nh ? nn : nh;

  char* ws = (char*)d_ws;
  size_t off = 0;
  auto alloc = [&](size_t b) { size_t r = off; off += (b + 255) & ~(size_t)255; return r; };
  size_t o_flag  = alloc(4);
  size_t o_rowN  = alloc((size_t)(nn + 1) * 4);
  size_t o_rowH  = alloc((size_t)(nh + 1) * 4);
  size_t o_gbcnt = alloc((size_t)(NBN + NBH) * 4);
  size_t o_w5t   = alloc((size_t)64 * 128 * 4);
  size_t o_pn    = alloc((size_t)E * 4);
  size_t o_ph    = alloc((size_t)E * 4);
  size_t o_po16  = alloc((size_t)nn * NODE_CH * 2);          // pout f16 [N,128]
  size_t o_qppp  = alloc((size_t)mx * Q_CH * 4);             // q_ppp [N,64] / later p_ppp [H,64]
  size_t o_G2    = alloc((size_t)nh * NODE_CH * 4);          // G2 [H,128] f32
  size_t o_pk1   = alloc((size_t)nh * 128 * 4);              // packed1 [H,128 u32] (512B rows)
  size_t o_t2    = o_pk1;                                     // t2 [H,128] f32 aliases packed1
  size_t need_stg = (size_t)MAX_NB * CAP * 4;
  size_t o_stgN  = o_pk1;   // staging N aliases packed1 (dead before gemms)
  size_t o_stgH  = o_G2;    // staging H aliases G2
  if ((size_t)nh * 128 * 4 < need_stg) return;
  if ((size_t)nh * NODE_CH * 4 < need_stg) return;
  if (off > ws_size) return;

  int* flag   = (int*)(ws + o_flag);
  int* rowN   = (int*)(ws + o_rowN);
  int* rowH   = (int*)(ws + o_rowH);
  int* gbcntN = (int*)(ws + o_gbcnt);
  int* gbcntH = gbcntN + NBN;
  float* w5t  = (float*)(ws + o_w5t);
  int* pn     = (int*)(ws + o_pn);
  int* ph     = (int*)(ws + o_ph);
  int* stgN   = (int*)(ws + o_stgN);
  int* stgH   = (int*)(ws + o_stgH);
  unsigned short* po16 = (unsigned short*)(ws + o_po16);
  float* qppp = (float*)(ws + o_qppp);
  float* pppp = qppp;                       // reuse after stage 1
  float* G2   = (float*)(ws + o_G2);
  unsigned int* pk1 = (unsigned int*)(ws + o_pk1);
  float* t2   = (float*)(ws + o_t2);

  hipMemsetAsync(gbcntN, 0, (size_t)(NBN + NBH) * 4, stream);
  detect_kernel<<<1, 64, 0, stream>>>((const unsigned int*)hidx, flag);
  transpose_w5<<<32, 256, 0, stream>>>(w5, w5t);

  int nblk = (int)((E + CHUNK - 1) / CHUNK);
  bin_kernel<<<nblk, 512, 0, stream>>>(hidx, flag, stgN, stgH, gbcntN, gbcntH, E, NBN, NBH);
  int nbmax = NBN > NBH ? NBN : NBH;
  bucket_sort_kernel<<<dim3(nbmax, 2), 512, 0, stream>>>(
      stgN, gbcntN, rowN, pn, nn, NBN,
      stgH, gbcntH, rowH, ph, nh, NBH, E);

  // stage-1 inputs: packed1 = [q_pp f32 | q_p f16], segv = q_ppp
  gemm_f32<<<dim3(Q_CH / GBN,    (nh + GBM - 1) / GBM), 256, 0, stream>>>(
      q, w2, (float*)pk1, 128, nullptr, 0, 0, nh, Q_CH, IN_CH);
  gemm_f32<<<dim3(NODE_CH / GBN, (nh + GBM - 1) / GBM), 256, 0, stream>>>(
      q, w1, nullptr, 0, (unsigned short*)pk1, 256, 128, nh, NODE_CH, IN_CH);
  gemm_f32<<<dim3(Q_CH / GBN,    (nn + GBM - 1) / GBM), 256, 0, stream>>>(
      p, w3, qppp, Q_CH, nullptr, 0, 0, nn, Q_CH, NODE_CH);

  stage1_fused<<<(nn + 3) / 4, 256, 0, stream>>>(rowN, pn, qppp, pk1, po16, nn);

  // stage-2 inputs: p_ppp = q@w6 (reuses qppp buffer), G2 = p_ppp @ w5^T
  gemm_f32<<<dim3(Q_CH / GBN,    (nh + GBM - 1) / GBM), 256, 0, stream>>>(
      q, w6, pppp, Q_CH, nullptr, 0, 0, nh, Q_CH, IN_CH);
  gemm_f32<<<dim3(NODE_CH / GBN, (nh + GBM - 1) / GBM), 256, 0, stream>>>(
      pppp, w5t, G2, NODE_CH, nullptr, 0, 0, nh, NODE_CH, Q_CH);

  stage2_fused<<<(nh + 3) / 4, 256, 0, stream>>>(rowH, ph, G2, (const unsigned int*)po16, t2, nh);

  // q_out = t2 @ w4
  gemm_f32<<<dim3(OUT_CH / GBN, (nh + GBM - 1) / GBM), 256, 0, stream>>>(
      t2, w4, (float*)d_out, OUT_CH, nullptr, 0, 0, nh, OUT_CH, NODE_CH);
}